// Round 1
// 131.827 us; speedup vs baseline: 1.0219x; 1.0219x over previous
//
#include <hip/hip_runtime.h>
#include <math.h>

// Problem constants
static constexpr int PB = 32;      // batch
static constexpr int PL = 4096;    // seq len
static constexpr int PC = 64;      // in channels
static constexpr int PD = 128;     // out channels
static constexpr int PK = 2048;    // TOPK = L/2

typedef __attribute__((ext_vector_type(8))) short bf16x8;
typedef __attribute__((ext_vector_type(4))) float f32x4;

#define MFMA_BF16(A, B, C) __builtin_amdgcn_mfma_f32_16x16x32_bf16(A, B, C, 0, 0, 0)

__device__ inline short f2bf(float f) {
  unsigned u = __float_as_uint(f);
  u += 0x7FFFu + ((u >> 16) & 1u);   // RNE
  return (short)(u >> 16);
}

// ---------------- kernel 1: scores (B,L) + x->bf16 copy + W panel transforms --
// float4 loads (16 B/lane). Block = 256 threads = 16 rows.
// Blocks 0/1 additionally transform sparse_w/full_w (f32 CxD) into
// fragment-ordered bf16 panels in workspace:
//   u32[(((t*2+h)*4 + quad)*16 + ln)*4 + jp] = bf16{W[c][d], W[c+1][d]}
//   where d = t*16+ln (output col), c = h*32+quad*8+2*jp (k index).
// This is exactly the per-lane order the MFMA B-fragment reads, so LDS
// reads in the GEMM kernels are contiguous 1024B per wave (conflict-free).
__global__ __launch_bounds__(256) void scores_kernel(
    const float* __restrict__ x, const float* __restrict__ score_w,
    const float* __restrict__ score_b, const float* __restrict__ sparse_w,
    const float* __restrict__ full_w, float* __restrict__ scores,
    short* __restrict__ xbf, unsigned* __restrict__ wtfg) {
  int tid = threadIdx.x;

  if (blockIdx.x < 2) {
    const float* w = (blockIdx.x == 0) ? sparse_w : full_w;
    unsigned* dst = wtfg + blockIdx.x * 4096;
    for (int i = tid; i < 4096; i += 256) {
      int d = i & 127, cp = i >> 7, c = cp * 2;
      float va = w[(size_t)c * PD + d];
      float vb = w[(size_t)(c + 1) * PD + d];
      unsigned lo = (unsigned short)f2bf(va);
      unsigned hi = (unsigned short)f2bf(vb);
      int t = d >> 4, dl = d & 15, h = c >> 5, cq = (c >> 3) & 3, jp = (c & 7) >> 1;
      dst[(((t * 2 + h) * 4 + cq) * 16 + dl) * 4 + jp] = lo | (hi << 16);
    }
  }

  int r  = tid >> 4;
  int c4 = tid & 15;
  int row = blockIdx.x * 16 + r;                 // grid covers B*L/16 exactly
  float4 xv = *(const float4*)(x + (size_t)row * PC + c4 * 4);
  float4 wv = *(const float4*)(score_w + c4 * 4);

  // bf16 copy of x (RNE, identical bits to what the GEMM kernels used to make)
  short4 xbv;
  xbv.x = f2bf(xv.x); xbv.y = f2bf(xv.y); xbv.z = f2bf(xv.z); xbv.w = f2bf(xv.w);
  *(short4*)(xbf + (size_t)row * PC + c4 * 4) = xbv;

  float v = xv.x * wv.x + xv.y * wv.y + xv.z * wv.z + xv.w * wv.w;
  #pragma unroll
  for (int off = 1; off < 16; off <<= 1) v += __shfl_xor(v, off);
  if (c4 == 0) scores[row] = v + score_b[0];
}

// ---------------- kernel 2: exact top-K selection per batch ----------------
// one block (256 threads = 4 waves) per batch; radix-select over sortable uint
// keys, ties at threshold broken by lowest index (matches lax.top_k).
__global__ __launch_bounds__(256) void select_kernel(
    const float* __restrict__ scores, int* __restrict__ selidx,
    float* __restrict__ agg) {
  __shared__ unsigned hist4[4 * 256];   // per-wave histograms, 4 KB
  __shared__ unsigned sbuf[257];
  __shared__ unsigned wsum[4];
  __shared__ unsigned sh_prefix, sh_need;

  int tid = threadIdx.x;
  int lane = tid & 63;
  int wid  = tid >> 6;
  int b = blockIdx.x;
  const float* sc = scores + (size_t)b * PL;

  // stage 16 keys into registers (4 coalesced float4 loads)
  unsigned k[16];
  #pragma unroll
  for (int q = 0; q < 4; ++q) {
    float4 f = *(const float4*)(sc + tid * 16 + q * 4);
    unsigned u0 = __float_as_uint(f.x), u1 = __float_as_uint(f.y);
    unsigned u2 = __float_as_uint(f.z), u3 = __float_as_uint(f.w);
    k[q * 4 + 0] = (u0 & 0x80000000u) ? ~u0 : (u0 | 0x80000000u);
    k[q * 4 + 1] = (u1 & 0x80000000u) ? ~u1 : (u1 | 0x80000000u);
    k[q * 4 + 2] = (u2 & 0x80000000u) ? ~u2 : (u2 | 0x80000000u);
    k[q * 4 + 3] = (u3 & 0x80000000u) ? ~u3 : (u3 | 0x80000000u);
  }

  if (tid == 0) { sh_prefix = 0u; sh_need = (unsigned)PK; sbuf[256] = 0u; }
  // zero agg for this batch (sparse_kernel accumulates into it later)
  if (tid < PD) agg[(size_t)b * PD + tid] = 0.f;

  // 4 radix rounds, MSB first
  for (int r = 3; r >= 0; --r) {
    int shift = r * 8;
    #pragma unroll
    for (int w = 0; w < 4; ++w) hist4[w * 256 + tid] = 0u;
    __syncthreads();                      // also publishes sh_prefix/sh_need
    unsigned prefix = sh_prefix;
    unsigned need   = sh_need;
    unsigned maskAbove = (r == 3) ? 0u : (~0u << (shift + 8));
    unsigned* myhist = &hist4[wid * 256];
    #pragma unroll
    for (int j = 0; j < 16; ++j) {
      if ((k[j] & maskAbove) == prefix)
        atomicAdd(&myhist[(k[j] >> shift) & 255u], 1u);
    }
    __syncthreads();
    // merge 4 copies + inclusive suffix sum via wave shfl (bucket = tid)
    unsigned v = hist4[tid] + hist4[256 + tid] + hist4[512 + tid] + hist4[768 + tid];
    #pragma unroll
    for (int off = 1; off < 64; off <<= 1) {
      unsigned t = __shfl_down(v, off);
      if (lane + off < 64) v += t;
    }
    if (lane == 0) wsum[wid] = v;         // sum of this wave's 64 buckets
    __syncthreads();
    unsigned add = 0;
    #pragma unroll
    for (int w = 0; w < 4; ++w) if (w > wid) add += wsum[w];
    sbuf[tid] = v + add;
    __syncthreads();
    // suffix non-increasing; unique boundary: sbuf[d]>=need, sbuf[d+1]<need
    if (sbuf[tid] >= need && sbuf[tid + 1] < need) {
      sh_prefix = prefix | ((unsigned)tid << shift);
      sh_need = need - sbuf[tid + 1];
    }
  }
  __syncthreads();
  unsigned T = sh_prefix;       // K-th largest key
  unsigned needEq = sh_need;    // how many ==T to take (lowest indices)

  // each thread owns 16 contiguous indices (base = tid*16), keys in regs
  int base = tid * 16;
  unsigned ceq = 0;
  #pragma unroll
  for (int j = 0; j < 16; ++j) ceq += (k[j] == T);

  // exclusive prefix scan of eq counts (wave shfl + cross-wave)
  unsigned v1 = ceq;
  #pragma unroll
  for (int off = 1; off < 64; off <<= 1) {
    unsigned t = __shfl_up(v1, off);
    if (lane >= off) v1 += t;
  }
  if (lane == 63) wsum[wid] = v1;
  __syncthreads();
  unsigned add1 = 0;
  #pragma unroll
  for (int w = 0; w < 4; ++w) if (w < wid) add1 += wsum[w];
  unsigned eqbase = v1 + add1 - ceq;
  __syncthreads();                        // protect wsum before reuse

  // count selected in my chunk
  unsigned csel = 0, eqr = eqbase;
  #pragma unroll
  for (int j = 0; j < 16; ++j) {
    if (k[j] > T) csel++;
    else if (k[j] == T) { if (eqr < needEq) csel++; eqr++; }
  }
  unsigned v2 = csel;
  #pragma unroll
  for (int off = 1; off < 64; off <<= 1) {
    unsigned t = __shfl_up(v2, off);
    if (lane >= off) v2 += t;
  }
  if (lane == 63) wsum[wid] = v2;
  __syncthreads();
  unsigned add2 = 0;
  #pragma unroll
  for (int w = 0; w < 4; ++w) if (w < wid) add2 += wsum[w];
  unsigned pos = v2 + add2 - csel;

  // write compacted indices
  eqr = eqbase;
  int* outp = selidx + (size_t)b * PK;
  #pragma unroll
  for (int j = 0; j < 16; ++j) {
    bool sel;
    if (k[j] > T) sel = true;
    else if (k[j] == T) { sel = (eqr < needEq); eqr++; }
    else sel = false;
    if (sel) outp[pos++] = base + j;
  }
}

// ---------------- shared staging: 16 KB fragment-ordered W panel -> LDS ------
// Pure vector copy: 4 x (dwordx4 load + b128 LDS write) per thread. No VALU
// conversion work; layout in global already matches MFMA fragment read order.
__device__ inline void stage_wtf(const unsigned* __restrict__ g, unsigned* lds, int tid) {
  #pragma unroll
  for (int q = 0; q < 4; ++q) {
    uint4 v = *(const uint4*)(g + q * 1024 + tid * 4);
    *(uint4*)(lds + q * 1024 + tid * 4) = v;
  }
}

// ---------------- kernel 3: sparse GEMM + gelu + sum into agg ----------------
// block = 256 = 4 waves; each wave: 32 selected rows (2 groups of 16) x 128
// cols via MFMA. B-fragments reused across both row groups (ds:MFMA = 1:2).
__global__ __launch_bounds__(256, 3) void sparse_kernel(
    const short* __restrict__ xbf, const unsigned* __restrict__ wtfg,
    const float* __restrict__ sparse_b, const int* __restrict__ selidx,
    float* __restrict__ agg) {
  __shared__ unsigned WTf[4096];   // 16 KB
  __shared__ float red[PD];
  int tid = threadIdx.x;
  stage_wtf(wtfg, WTf, tid);
  if (tid < PD) red[tid] = 0.f;
  __syncthreads();

  int lane = tid & 63, wid = tid >> 6;
  int ln = lane & 15, quad = lane >> 4;
  int b  = blockIdx.x >> 4;            // 16 row-blocks of 128 per batch
  int rb = blockIdx.x & 15;
  int j0 = rb * 128 + wid * 32 + ln;   // selected slots j0 and j0+16
  const int* sel = selidx + (size_t)b * PK;
  int r0 = sel[j0], r1 = sel[j0 + 16];

  const short* xb = xbf + (size_t)b * PL * PC;
  const short* p0 = xb + (size_t)r0 * PC + quad * 8;
  const short* p1 = xb + (size_t)r1 * PC + quad * 8;
  bf16x8 a00 = *(const bf16x8*)p0, a01 = *(const bf16x8*)(p0 + 32);
  bf16x8 a10 = *(const bf16x8*)p1, a11 = *(const bf16x8*)(p1 + 32);

  f32x4 acc0[8], acc1[8];
  #pragma unroll
  for (int t = 0; t < 8; ++t) { acc0[t] = (f32x4){0.f,0.f,0.f,0.f}; acc1[t] = (f32x4){0.f,0.f,0.f,0.f}; }

  const short* wb = (const short*)WTf + lane * 8;   // contiguous per-wave reads
  #pragma unroll
  for (int t = 0; t < 8; ++t) {
    bf16x8 b0 = *(const bf16x8*)(wb + (2 * t) * 512);
    bf16x8 b1 = *(const bf16x8*)(wb + (2 * t + 1) * 512);
    acc0[t] = MFMA_BF16(a00, b0, acc0[t]);
    acc0[t] = MFMA_BF16(a01, b1, acc0[t]);
    acc1[t] = MFMA_BF16(a10, b0, acc1[t]);
    acc1[t] = MFMA_BF16(a11, b1, acc1[t]);
  }

  // gelu(feat + bias), sum over this wave's 32 rows per column
  #pragma unroll
  for (int t = 0; t < 8; ++t) {
    float bias = sparse_b[t * 16 + ln];
    float s = 0.f;
    #pragma unroll
    for (int i = 0; i < 4; ++i) {
      float v0 = acc0[t][i] + bias;
      s += 0.5f * v0 * (1.0f + erff(v0 * 0.70710678118654752f));
      float v1 = acc1[t][i] + bias;
      s += 0.5f * v1 * (1.0f + erff(v1 * 0.70710678118654752f));
    }
    s += __shfl_xor(s, 16);
    s += __shfl_xor(s, 32);     // sum over all 32 rows of the wave
    if (quad == 0) atomicAdd(&red[t * 16 + ln], s);
  }
  __syncthreads();
  if (tid < PD) atomicAdd(&agg[(size_t)b * PD + tid], red[tid]);
}

// ---------------- kernel 4: full GEMM + agg + LayerNorm + store -------------
// block = 256 = 4 waves; each wave: 32 rows (2 groups of 16) x 128 cols.
__global__ __launch_bounds__(256, 3) void full_ln_kernel(
    const short* __restrict__ xbf, const unsigned* __restrict__ wtfg,
    const float* __restrict__ full_b, const float* __restrict__ ln_g,
    const float* __restrict__ ln_b, const float* __restrict__ agg,
    float* __restrict__ out) {
  __shared__ unsigned WTf[4096];   // 16 KB
  int tid = threadIdx.x;
  stage_wtf(wtfg, WTf, tid);
  __syncthreads();

  int lane = tid & 63, wid = tid >> 6;
  int ln = lane & 15, quad = lane >> 4;
  int rowbase = blockIdx.x * 128 + wid * 32;   // 32 rows per wave
  int b = rowbase >> 12;                       // L = 4096

  const float invK = 1.0f / (float)PK;
  float bias[8], gg[8], bb[8];
  #pragma unroll
  for (int t = 0; t < 8; ++t) {
    int d = t * 16 + ln;
    bias[t] = full_b[d] + agg[(size_t)b * PD + d] * invK;
    gg[t] = ln_g[d];
    bb[t] = ln_b[d];
  }

  const short* p0 = xbf + (size_t)(rowbase + ln) * PC + quad * 8;
  const short* p1 = xbf + (size_t)(rowbase + 16 + ln) * PC + quad * 8;
  bf16x8 a00 = *(const bf16x8*)p0, a01 = *(const bf16x8*)(p0 + 32);
  bf16x8 a10 = *(const bf16x8*)p1, a11 = *(const bf16x8*)(p1 + 32);

  f32x4 acc0[8], acc1[8];
  #pragma unroll
  for (int t = 0; t < 8; ++t) { acc0[t] = (f32x4){0.f,0.f,0.f,0.f}; acc1[t] = (f32x4){0.f,0.f,0.f,0.f}; }

  const short* wb = (const short*)WTf + lane * 8;
  #pragma unroll
  for (int t = 0; t < 8; ++t) {
    bf16x8 b0 = *(const bf16x8*)(wb + (2 * t) * 512);
    bf16x8 b1 = *(const bf16x8*)(wb + (2 * t + 1) * 512);
    acc0[t] = MFMA_BF16(a00, b0, acc0[t]);
    acc0[t] = MFMA_BF16(a01, b1, acc0[t]);
    acc1[t] = MFMA_BF16(a10, b0, acc1[t]);
    acc1[t] = MFMA_BF16(a11, b1, acc1[t]);
  }

  // h = feat + bias; LayerNorm per row (row = rowbase + goff + quad*4 + i,
  // its 128 cols live on the 16 lanes of this quad x 8 tiles)
#define LN_EPILOGUE(ACC, GOFF) do {                                          \
    float s_[4] = {0.f,0.f,0.f,0.f}, ss_[4] = {0.f,0.f,0.f,0.f};             \
    _Pragma("unroll")                                                        \
    for (int t = 0; t < 8; ++t) {                                            \
      _Pragma("unroll")                                                      \
      for (int i = 0; i < 4; ++i) {                                          \
        float h_ = ACC[t][i] + bias[t];                                      \
        ACC[t][i] = h_;                                                      \
        s_[i] += h_; ss_[i] += h_ * h_;                                      \
      }                                                                      \
    }                                                                        \
    _Pragma("unroll")                                                        \
    for (int i = 0; i < 4; ++i) {                                            \
      _Pragma("unroll")                                                      \
      for (int off = 1; off < 16; off <<= 1) {                               \
        s_[i]  += __shfl_xor(s_[i], off);                                    \
        ss_[i] += __shfl_xor(ss_[i], off);                                   \
      }                                                                      \
    }                                                                        \
    _Pragma("unroll")                                                        \
    for (int i = 0; i < 4; ++i) {                                            \
      float mu_  = s_[i] * (1.0f / 128.0f);                                  \
      float var_ = ss_[i] * (1.0f / 128.0f) - mu_ * mu_;                     \
      float inv_ = rsqrtf(var_ + 1e-5f);                                     \
      int r_ = rowbase + (GOFF) + quad * 4 + i;                              \
      float* op_ = out + (size_t)r_ * PD + ln;                               \
      _Pragma("unroll")                                                      \
      for (int t = 0; t < 8; ++t)                                            \
        op_[t * 16] = (ACC[t][i] - mu_) * inv_ * gg[t] + bb[t];              \
    }                                                                        \
  } while (0)

  LN_EPILOGUE(acc0, 0);
  LN_EPILOGUE(acc1, 16);
#undef LN_EPILOGUE
}

// ---------------- launcher ----------------
extern "C" void kernel_launch(void* const* d_in, const int* in_sizes, int n_in,
                              void* d_out, int out_size, void* d_ws, size_t ws_size,
                              hipStream_t stream) {
  const float* x        = (const float*)d_in[0];
  const float* score_w  = (const float*)d_in[1];
  const float* score_b  = (const float*)d_in[2];
  const float* sparse_w = (const float*)d_in[3];
  const float* sparse_b = (const float*)d_in[4];
  const float* full_w   = (const float*)d_in[5];
  const float* full_b   = (const float*)d_in[6];
  const float* ln_g     = (const float*)d_in[7];
  const float* ln_b     = (const float*)d_in[8];
  float* out = (float*)d_out;

  char* ws = (char*)d_ws;
  float*    scores = (float*)ws;                       // B*L f32      (512 KB)
  int*      selidx = (int*)(ws + (512 << 10));         // B*K i32      (256 KB)
  float*    agg    = (float*)(ws + (768 << 10));       // B*D f32      (16 KB)
  unsigned* wtfg   = (unsigned*)(ws + (784 << 10));    // 2 W panels   (32 KB)
  short*    xbf    = (short*)(ws + (816 << 10));       // B*L*C bf16   (16 MB)

  scores_kernel<<<PB * PL / 16, 256, 0, stream>>>(x, score_w, score_b, sparse_w,
                                                  full_w, scores, xbf, wtfg);
  select_kernel<<<PB, 256, 0, stream>>>(scores, selidx, agg);
  sparse_kernel<<<PB * (PK / 128), 256, 0, stream>>>(xbf, wtfg, sparse_b, selidx, agg);
  full_ln_kernel<<<PB * PL / 128, 256, 0, stream>>>(xbf, wtfg + 4096, full_b,
                                                    ln_g, ln_b, agg, out);
}